// Round 1
// baseline (1660.896 us; speedup 1.0000x reference)
//
#include <hip/hip_runtime.h>
#include <hip/hip_bf16.h>
#include <math.h>

#define NN 8192
#define EE 131072
#define HH 256
#define LL 3
#define RR 128
#define NGG 64
#define MSG_WAVES 16         // waves per k_msg block (1024 threads)
#define CHUNK 16             // edges per wave: EE/CHUNK = 8192 waves, perfectly uniform

typedef __attribute__((ext_vector_type(8))) short bf16x8;
typedef __attribute__((ext_vector_type(4))) float f32x4;
typedef unsigned short u16;

#if defined(__has_builtin)
#if __has_builtin(__builtin_amdgcn_fdot2_f32_bf16)
#define HAVE_FDOT2 1
typedef __attribute__((ext_vector_type(2))) __bf16 bf16x2_t;
union BU { unsigned u; bf16x2_t v; };
#endif
#if __has_builtin(__builtin_amdgcn_global_load_lds)
#define HAVE_GLL 1
#endif
#endif

union U4 { ushort4 v; unsigned short a[4]; };
union U8 { uint4 v; unsigned short a[8]; unsigned w[4]; };

__device__ __forceinline__ float silu(float v) { return v / (1.0f + expf(-v)); }
__device__ __forceinline__ float b2f(unsigned short u) { return __uint_as_float(((unsigned)u) << 16); }
__device__ __forceinline__ unsigned short f2b(float f) {
    unsigned u = __float_as_uint(f);
    u += 0x7fff + ((u >> 16) & 1);
    return (unsigned short)(u >> 16);
}

constexpr float kInvSqrt2 = 0.70710678118654752440f;
constexpr float kInvSqrt3 = 0.57735026918962576451f;
constexpr float kInvSqrtH = 0.0625f; // 1/sqrt(256)

// ---------------- utility ----------------
__global__ void k_zero(float* __restrict__ p, int n4) {
    int i = blockIdx.x * 256 + threadIdx.x;
    if (i < n4) ((float4*)p)[i] = make_float4(0.f, 0.f, 0.f, 0.f);
}

// ---------------- ALL weight prep in one launch ----------------
// transpose in[K,N] fp32 -> out[N,K] bf16; rbf_w: row-PAIR interleaved k-major bf16
__global__ __launch_bounds__(256) void k_wt_all(
    const float* __restrict__ xp_w1, const float* __restrict__ xp_w2,
    const float* __restrict__ rbf_w, const float* __restrict__ vec_w,
    const float* __restrict__ xv_w1, const float* __restrict__ xv_w2,
    const float* __restrict__ oe_w1,
    u16* __restrict__ xp_w1T, u16* __restrict__ xp_w2T, u16* __restrict__ rbf_wP,
    u16* __restrict__ vec_wT, u16* __restrict__ xv_w1T, u16* __restrict__ xv_w2T,
    u16* __restrict__ oe_w1T) {
    int bid = blockIdx.x;
    const float* src; u16* dst; int K, N, t, pairmode = 0;
    if (bid < 2400) {
        int l = bid / 800, r = bid % 800;
        if (r < 64)       { src = xp_w1 + (size_t)l * 65536;  dst = xp_w1T + (size_t)l * 65536;  K = 256; N = 256; t = r; }
        else if (r < 256) { src = xp_w2 + (size_t)l * 196608; dst = xp_w2T + (size_t)l * 196608; K = 256; N = 768; t = r - 64; }
        else if (r < 352) { src = rbf_w + (size_t)l * 98304;  dst = rbf_wP + (size_t)l * 98304;  K = 128; N = 768; t = r - 256; pairmode = 1; }
        else if (r < 480) { src = vec_w + (size_t)l * 131072; dst = vec_wT + (size_t)l * 131072; K = 256; N = 512; t = r - 352; }
        else if (r < 608) { src = xv_w1 + (size_t)l * 131072; dst = xv_w1T + (size_t)l * 131072; K = 512; N = 256; t = r - 480; }
        else              { src = xv_w2 + (size_t)l * 196608; dst = xv_w2T + (size_t)l * 196608; K = 256; N = 768; t = r - 608; }
    } else {
        src = oe_w1; dst = oe_w1T; K = 256; N = 128; t = bid - 2400;
    }
    int nx = N >> 5;
    int bn = (t % nx) * 32, bk = (t / nx) * 32;
    int tx = threadIdx.x & 31, ty = threadIdx.x >> 5;   // 32 x 8
    if (pairmode) {
#pragma unroll
        for (int i = 0; i < 32; i += 8) {
            int k = bk + ty + i, n = bn + tx;
            dst[(size_t)(k >> 1) * 1536 + n * 2 + (k & 1)] = f2b(src[(size_t)k * N + n]);
        }
        return;
    }
    __shared__ float tile[32][33];
#pragma unroll
    for (int i = 0; i < 32; i += 8)
        tile[ty + i][tx] = src[(size_t)(bk + ty + i) * N + bn + tx];
    __syncthreads();
#pragma unroll
    for (int i = 0; i < 32; i += 8)
        dst[(size_t)(bn + ty + i) * K + bk + tx] = f2b(tile[tx][ty + i]);
}

// ---------------- init: x = atom_emb[z], + LayerNorm(ln[0]) -> xlnb ----------------
__global__ void k_init_ln(const float* __restrict__ emb, const int* __restrict__ z,
                          const float* __restrict__ w, const float* __restrict__ b,
                          float* __restrict__ x, u16* __restrict__ xlnb) {
    int n = blockIdx.x, t = threadIdx.x;
    float v = emb[z[n] * HH + t];
    x[(size_t)n * HH + t] = v;
    float s = v, q = v * v;
#pragma unroll
    for (int m = 32; m >= 1; m >>= 1) {
        s += __shfl_xor(s, m, 64);
        q += __shfl_xor(q, m, 64);
    }
    __shared__ float s_sum[4], s_sq[4];
    int wid = t >> 6;
    if ((t & 63) == 0) { s_sum[wid] = s; s_sq[wid] = q; }
    __syncthreads();
    float S = s_sum[0] + s_sum[1] + s_sum[2] + s_sum[3];
    float Q = s_sq[0] + s_sq[1] + s_sq[2] + s_sq[3];
    float mu = S * (1.0f / HH);
    float var = Q * (1.0f / HH) - mu * mu;
    float rs = rsqrtf(var + 1e-5f);
    xlnb[(size_t)n * HH + t] = f2b((v - mu) * rs * w[t] + b[t]);
}

// ---------------- edge geometry + degree histogram (fused) ----------------
__global__ void k_geom_hist(const float* __restrict__ pos, const int* __restrict__ ei,
                            float* __restrict__ ev, int* __restrict__ deg) {
    int e = blockIdx.x * 256 + threadIdx.x;
    if (e >= EE) return;
    int s = ei[e], d = ei[EE + e];
    float rx = pos[s * 3 + 0] - pos[d * 3 + 0];
    float ry = pos[s * 3 + 1] - pos[d * 3 + 1];
    float rz = pos[s * 3 + 2] - pos[d * 3 + 2];
    float dist = sqrtf(rx * rx + ry * ry + rz * rz);
    float inv = 1.0f / dist;
    ((float4*)ev)[e] = make_float4(rx * inv, ry * inv, rz * inv, dist);
    atomicAdd(&deg[d], 1);
}

// ---------------- scan (CSR offsets -> fill), one block ---------------
__global__ void k_scan(const int* __restrict__ deg, int* __restrict__ fill) {
    __shared__ int buf[256];
    __shared__ int carry_s;
    int t = threadIdx.x;
    if (t == 0) carry_s = 0;
    __syncthreads();
    for (int r = 0; r < NN; r += 256) {
        int v = deg[r + t];
        buf[t] = v;
        __syncthreads();
        for (int ofs = 1; ofs < 256; ofs <<= 1) {
            int add = (t >= ofs) ? buf[t - ofs] : 0;
            __syncthreads();
            buf[t] += add;
            __syncthreads();
        }
        int excl = buf[t] - v;
        int carry = carry_s;
        fill[r + t] = carry + excl;
        __syncthreads();
        if (t == 255) carry_s = carry + buf[t];
        __syncthreads();
    }
}

// scatter + gaussian window: 8 rows, EVEN-aligned k0; gtab packed bf16 pairs (16B)
__global__ void k_scatter(const int* __restrict__ ei, const float* __restrict__ ev,
                          int* __restrict__ fill, int* __restrict__ srcp,
                          float4* __restrict__ evp, int* __restrict__ kptab,
                          unsigned* __restrict__ gtab, int* __restrict__ dstp) {
    int e = blockIdx.x * 256 + threadIdx.x;
    if (e >= EE) return;
    int d = ei[EE + e];
    int pos = atomicAdd(&fill[d], 1);
    float4 e4 = ((const float4*)ev)[e];
    srcp[pos] = ei[e];
    dstp[pos] = d;
    evp[pos] = e4;
    const float step = 12.0f / 127.0f;
    const float coeff = -0.5f / (step * step);
    float dist = e4.w;
    int k0 = ((int)floorf(dist / step) - 3) & ~1;   // even-aligned
    k0 = k0 < 0 ? 0 : (k0 > 120 ? 120 : k0);
    float g[8];
#pragma unroll
    for (int k = 0; k < 8; ++k) {
        float t = dist - (k0 + k) * step;
        g[k] = expf(coeff * t * t);
    }
    kptab[pos] = k0 >> 1;
    unsigned g0 = (unsigned)f2b(g[0]) | ((unsigned)f2b(g[1]) << 16);
    unsigned g1 = (unsigned)f2b(g[2]) | ((unsigned)f2b(g[3]) << 16);
    unsigned g2 = (unsigned)f2b(g[4]) | ((unsigned)f2b(g[5]) << 16);
    unsigned g3 = (unsigned)f2b(g[6]) | ((unsigned)f2b(g[7]) << 16);
    ((uint4*)gtab)[pos] = make_uint4(g0, g1, g2, g3);
}

// ---------------- bf16 MFMA GEMM: C = act(A[M,K] @ BT[N,K]^T + bias) ----------------
template <int OUT_BF16, int ACT>
__global__ __launch_bounds__(256) void k_gemm(
    const u16* __restrict__ A, const u16* __restrict__ BT,
    const float* __restrict__ bias, void* __restrict__ C, int M, int K, int N) {
    __shared__ u16 As[4096];   // [128 rows][32 k] bf16 = 8 KB
    __shared__ u16 Bs[4096];
    int tid = threadIdx.x;
    int wave = tid >> 6, lane = tid & 63;
    int bm = blockIdx.y * 128, bn = blockIdx.x * 128;
    int wm = (wave >> 1) * 64, wn = (wave & 1) * 64;
    int lm = lane & 15;
    int kg = lane >> 4;
    f32x4 acc[4][4] = {};

    for (int k0 = 0; k0 < K; k0 += 32) {
#pragma unroll
        for (int it = 0; it < 2; ++it) {
            int idx = it * 256 + tid;
            int r = idx >> 2, seg = idx & 3;
#ifdef HAVE_GLL
            __builtin_amdgcn_global_load_lds(
                (const unsigned*)&A[(size_t)(bm + r) * K + k0 + seg * 8],
                (unsigned*)&As[idx * 8], 16, 0, 0);
            __builtin_amdgcn_global_load_lds(
                (const unsigned*)&BT[(size_t)(bn + r) * K + k0 + seg * 8],
                (unsigned*)&Bs[idx * 8], 16, 0, 0);
#else
            *(uint4*)&As[idx * 8] = *(const uint4*)&A[(size_t)(bm + r) * K + k0 + seg * 8];
            *(uint4*)&Bs[idx * 8] = *(const uint4*)&BT[(size_t)(bn + r) * K + k0 + seg * 8];
#endif
        }
        __syncthreads();
        bf16x8 af[4], bfr[4];
#pragma unroll
        for (int i = 0; i < 4; ++i)
            af[i] = *(const bf16x8*)&As[(wm + i * 16 + lm) * 32 + kg * 8];
#pragma unroll
        for (int j = 0; j < 4; ++j)
            bfr[j] = *(const bf16x8*)&Bs[(wn + j * 16 + lm) * 32 + kg * 8];
#pragma unroll
        for (int i = 0; i < 4; ++i)
#pragma unroll
            for (int j = 0; j < 4; ++j)
                acc[i][j] = __builtin_amdgcn_mfma_f32_16x16x32_bf16(af[i], bfr[j], acc[i][j], 0, 0, 0);
        __syncthreads();
    }

#pragma unroll
    for (int j = 0; j < 4; ++j) {
        int col = bn + wn + j * 16 + lm;
        float bv = bias ? bias[col] : 0.f;
#pragma unroll
        for (int i = 0; i < 4; ++i) {
            int row0 = bm + wm + i * 16 + kg * 4;
#pragma unroll
            for (int r = 0; r < 4; ++r) {
                float v = acc[i][j][r] + bv;
                if (ACT) v = silu(v);
                if (OUT_BF16)
                    ((u16*)C)[(size_t)(row0 + r) * N + col] = f2b(v);
                else
                    ((float*)C)[(size_t)(row0 + r) * N + col] = v;
            }
        }
    }
}

// ---------------- fused message pass: BALANCED fixed-size edge chunks ----------------
// Every wave processes exactly CHUNK edges of the dst-sorted edge array (3 panels).
// Per-node partial sums are flushed with fire-and-forget f32 atomics into accX/accV;
// node boundaries inside a chunk are wave-uniform (dstp[j] same for all lanes).
__global__ __launch_bounds__(1024) void k_msg(
    const u16* __restrict__ xhb, const u16* __restrict__ vinb,
    const int* __restrict__ srcp, const float4* __restrict__ evp,
    const int* __restrict__ dstp, const int* __restrict__ kptab,
    const unsigned* __restrict__ gtab, const u16* __restrict__ WP /*pair-interleaved*/,
    const float* __restrict__ rbias,
    float* __restrict__ accX, float* __restrict__ accV) {
    __shared__ u16 Wp[64 * 512];    // 64 KB: [64 row-pairs][256 cols][2]
    int tid = threadIdx.x;
    int wave = tid >> 6, lane = tid & 63;
    int c0 = lane * 4;
    int E0 = (blockIdx.x * MSG_WAVES + wave) * CHUNK;
    int E1 = E0 + CHUNK;

#pragma unroll
    for (int p = 0; p < 3; ++p) {
        __syncthreads();
#pragma unroll
        for (int it = 0; it < 4; ++it) {        // cooperative 64KB panel load
            int idx = it * 1024 + tid;          // 4096 uint4
            int r = idx >> 6;                   // 64 row-pairs, 64 uint4/pair
            int c8 = (idx & 63) * 8;
            *(uint4*)&Wp[r * 512 + c8] =
                *(const uint4*)&WP[(size_t)r * 1536 + p * 512 + c8];
        }
        __syncthreads();
        float4 bb = ((const float4*)(rbias + p * 256))[lane];
        float bias4[4] = {bb.x, bb.y, bb.z, bb.w};
        float acc[3][4] = {};                   // p==0 uses acc[0] only
        int dcur = dstp[E0];
        auto flush = [&](int dn) {
            if (p == 0) {
                float* q = accX + (size_t)dn * 256 + c0;
#pragma unroll
                for (int c = 0; c < 4; ++c) atomicAdd(q + c, acc[0][c]);
            } else {
                float* q = accV + (size_t)dn * 768 + c0;
#pragma unroll
                for (int k = 0; k < 3; ++k)
#pragma unroll
                    for (int c = 0; c < 4; ++c) atomicAdd(q + k * 256 + c, acc[k][c]);
            }
#pragma unroll
            for (int k = 0; k < 3; ++k)
#pragma unroll
                for (int c = 0; c < 4; ++c) acc[k][c] = 0.f;
        };
#pragma unroll 2
        for (int j = E0; j < E1; ++j) {
            int d = dstp[j];
            if (d != dcur) { flush(dcur); dcur = d; }   // wave-uniform branch
            int s = srcp[j];
            int kp = kptab[j];
            uint4 gt = ((const uint4*)gtab)[j];
            unsigned gp[4] = {gt.x, gt.y, gt.z, gt.w};
            float rr[4] = {bias4[0], bias4[1], bias4[2], bias4[3]};
#pragma unroll
            for (int p2 = 0; p2 < 4; ++p2) {
                U8 w;
                w.v = *(const uint4*)&Wp[(kp + p2) * 512 + c0 * 2];  // ds_read_b128
#ifdef HAVE_FDOT2
                BU gv; gv.u = gp[p2];
#pragma unroll
                for (int c = 0; c < 4; ++c) {
                    BU wv; wv.u = w.w[c];
                    rr[c] = __builtin_amdgcn_fdot2_f32_bf16(wv.v, gv.v, rr[c], false);
                }
#else
                float ge = b2f((u16)(gp[p2] & 0xffff));
                float go = b2f((u16)(gp[p2] >> 16));
#pragma unroll
                for (int c = 0; c < 4; ++c)
                    rr[c] += ge * b2f(w.a[2 * c]) + go * b2f(w.a[2 * c + 1]);
#endif
            }
            if (p == 0) {
                U4 X; X.v = *(const ushort4*)(xhb + (size_t)s * 768 + c0);
#pragma unroll
                for (int c = 0; c < 4; ++c) acc[0][c] += b2f(X.a[c]) * rr[c];
            } else if (p == 1) {
                U4 X, V0, V1, V2;
                X.v = *(const ushort4*)(xhb + (size_t)s * 768 + 256 + c0);
                V0.v = *(const ushort4*)(vinb + (size_t)s * 768 + c0);
                V1.v = *(const ushort4*)(vinb + (size_t)s * 768 + 256 + c0);
                V2.v = *(const ushort4*)(vinb + (size_t)s * 768 + 512 + c0);
#pragma unroll
                for (int c = 0; c < 4; ++c) {
                    float m1 = b2f(X.a[c]) * rr[c] * kInvSqrt3;
                    acc[0][c] += b2f(V0.a[c]) * m1;
                    acc[1][c] += b2f(V1.a[c]) * m1;
                    acc[2][c] += b2f(V2.a[c]) * m1;
                }
            } else {
                U4 X; X.v = *(const ushort4*)(xhb + (size_t)s * 768 + 512 + c0);
                float4 ev4 = evp[j];
#pragma unroll
                for (int c = 0; c < 4; ++c) {
                    float m2 = b2f(X.a[c]) * rr[c];
                    acc[0][c] += m2 * ev4.x;
                    acc[1][c] += m2 * ev4.y;
                    acc[2][c] += m2 * ev4.z;
                }
            }
        }
        flush(dcur);
    }
}

// ---------------- message epilogue: x=(x+accX)*c ; vecMb = bf16(vin + accV*c) -------
__global__ void k_msg_epi(const float* __restrict__ accX, const float* __restrict__ accV,
                          float* __restrict__ x, const float* __restrict__ vin,
                          u16* __restrict__ vecMb) {
    int n = blockIdx.x, t = threadIdx.x;
    if (t < 64) {
        size_t i = (size_t)n * 64 + t;           // float4 over x/accX
        float4 xv = ((float4*)x)[i];
        float4 av = ((const float4*)accX)[i];
        xv.x = (xv.x + av.x) * kInvSqrt2;
        xv.y = (xv.y + av.y) * kInvSqrt2;
        xv.z = (xv.z + av.z) * kInvSqrt2;
        xv.w = (xv.w + av.w) * kInvSqrt2;
        ((float4*)x)[i] = xv;
    } else {
        size_t i = (size_t)n * 192 + (t - 64);   // float4 over vin/accV (768 f = 192 f4)
        float4 vv = ((const float4*)vin)[i];
        float4 av = ((const float4*)accV)[i];
        ushort4 u;
        u.x = f2b(vv.x + av.x * kInvSqrtH);
        u.y = f2b(vv.y + av.y * kInvSqrtH);
        u.z = f2b(vv.z + av.z * kInvSqrtH);
        u.w = f2b(vv.w + av.w * kInvSqrtH);
        ((ushort4*)vecMb)[i] = u;
    }
}

// ---------------- vec_dot + hcat(bf16) = [x, vnorm]; vp in bf16 -------------------
__global__ void k_vecdot(const u16* __restrict__ vp, const float* __restrict__ x,
                         float* __restrict__ vec_dot, u16* __restrict__ hcat) {
    int i = blockIdx.x * 256 + threadIdx.x;  // N*H
    int n = i >> 8, c = i & 255;
    const u16* p = vp + (size_t)n * 1536;
    float dsum = 0.f, qsum = 0.f;
#pragma unroll
    for (int k = 0; k < 3; ++k) {
        float v1 = b2f(p[k * 512 + c]);
        float v2 = b2f(p[k * 512 + 256 + c]);
        dsum += v1 * v2;
        qsum += v2 * v2;
    }
    vec_dot[i] = dsum * kInvSqrtH;
    hcat[(size_t)n * 512 + c] = f2b(x[i]);
    hcat[(size_t)n * 512 + 256 + c] = f2b(sqrtf(qsum + 1e-8f));
}

// ---------------- update epilogue + fused LayerNorm; re-zeroes acc for next layer ---
__global__ void k_update_out(const u16* __restrict__ hout, const float* __restrict__ vec_dot,
                             const u16* __restrict__ vp, float* __restrict__ x,
                             const u16* __restrict__ vecMb, float* __restrict__ vfin,
                             u16* __restrict__ vb,
                             const float* __restrict__ lnw, const float* __restrict__ lnb,
                             u16* __restrict__ xout,
                             float* __restrict__ azX, float* __restrict__ azV) {
    int n = blockIdx.x, t = threadIdx.x;
    size_t i = (size_t)n * 256 + t;
    float xv1 = b2f(hout[(size_t)n * 768 + t]);
    float xv2 = b2f(hout[(size_t)n * 768 + 256 + t]);
    float xv3 = b2f(hout[(size_t)n * 768 + 512 + t]);
    float dxv = (xv1 + xv2 * vec_dot[i]) * kInvSqrt2;
    float nx = (x[i] + dxv) * kInvSqrt2;
    x[i] = nx;
#pragma unroll
    for (int k = 0; k < 3; ++k) {
        size_t idx = (size_t)n * 768 + k * 256 + t;
        float nv = b2f(vecMb[idx]) + xv3 * b2f(vp[(size_t)n * 1536 + k * 512 + t]);
        vfin[idx] = nv;
        vb[idx] = f2b(nv);
    }
    if (lnw) {
        float s = nx, q = nx * nx;
#pragma unroll
        for (int m = 32; m >= 1; m >>= 1) {
            s += __shfl_xor(s, m, 64);
            q += __shfl_xor(q, m, 64);
        }
        __shared__ float s_sum[4], s_sq[4];
        int wid = t >> 6;
        if ((t & 63) == 0) { s_sum[wid] = s; s_sq[wid] = q; }
        __syncthreads();
        float S = s_sum[0] + s_sum[1] + s_sum[2] + s_sum[3];
        float Q = s_sq[0] + s_sq[1] + s_sq[2] + s_sq[3];
        float mu = S * (1.0f / HH);
        float var = Q * (1.0f / HH) - mu * mu;
        float rs = rsqrtf(var + 1e-5f);
        xout[i] = f2b((nx - mu) * rs * lnw[t] + lnb[t]);
    } else {
        xout[i] = f2b(nx);
    }
    if (azV) {
        // re-zero next layer's atomic accumulators. accV aliases vpb: this block
        // only touches row n, and all row-n reads completed before the sync.
        __syncthreads();
        azX[i] = 0.f;
#pragma unroll
        for (int k = 0; k < 3; ++k) azV[(size_t)n * 768 + k * 256 + t] = 0.f;
    }
}

// ---------------- energy reduce ----------------
__global__ void k_energy2(const float* __restrict__ h, const float* __restrict__ w2,
                          const float* __restrict__ b2, const int* __restrict__ batch,
                          float* __restrict__ out) {
    __shared__ float g[NGG];
    int t = threadIdx.x;
    if (t < NGG) g[t] = 0.f;
    __syncthreads();
    int a = blockIdx.x * 256 + t;
    const float4* hr = (const float4*)(h + (size_t)a * 128);
    const float4* w4 = (const float4*)w2;
    float acc = 0.f;
#pragma unroll 8
    for (int i = 0; i < 32; ++i) {
        float4 hv = hr[i], wv = w4[i];
        acc += hv.x * wv.x + hv.y * wv.y + hv.z * wv.z + hv.w * wv.w;
    }
    acc += b2[0];
    atomicAdd(&g[batch[a]], acc);
    __syncthreads();
    if (t < NGG && g[t] != 0.f) atomicAdd(&out[t], g[t]);
}

extern "C" void kernel_launch(void* const* d_in, const int* in_sizes, int n_in,
                              void* d_out, int out_size, void* d_ws, size_t ws_size,
                              hipStream_t stream) {
    const float* pos      = (const float*)d_in[0];
    const float* atom_emb = (const float*)d_in[1];
    const float* ln_w     = (const float*)d_in[2];
    const float* ln_b     = (const float*)d_in[3];
    const float* xp_w1    = (const float*)d_in[4];
    const float* xp_b1    = (const float*)d_in[5];
    const float* xp_w2    = (const float*)d_in[6];
    const float* xp_b2    = (const float*)d_in[7];
    const float* rbf_w    = (const float*)d_in[8];
    const float* rbf_b    = (const float*)d_in[9];
    const float* vec_w    = (const float*)d_in[10];
    const float* xv_w1    = (const float*)d_in[11];
    const float* xv_b1    = (const float*)d_in[12];
    const float* xv_w2    = (const float*)d_in[13];
    const float* xv_b2    = (const float*)d_in[14];
    const float* oe_w1    = (const float*)d_in[15];
    const float* oe_b1    = (const float*)d_in[16];
    const float* oe_w2    = (const float*)d_in[17];
    const float* oe_b2    = (const float*)d_in[18];
    const int*   z        = (const int*)d_in[19];
    const int*   ei       = (const int*)d_in[20];
    const int*   batch    = (const int*)d_in[21];
    float* out = (float*)d_out;

    char* ws = (char*)d_ws;
    size_t off = 0;
    auto alloc = [&](size_t b) {
        void* p = ws + off;
        off = (off + b + 255) & ~(size_t)255;
        return p;
    };
    float*    x      = (float*)alloc((size_t)NN * HH * 4);       //   8 MB
    float*    vecA   = (float*)alloc((size_t)NN * 768 * 4);      //  24 MB  \ adjacent:
    u16*      vb     = (u16*)alloc((size_t)NN * 768 * 2);        //  12 MB  / joint zero
    u16*      vecMb  = (u16*)alloc((size_t)NN * 768 * 2);        //  12 MB
    u16*      xlnb   = (u16*)alloc((size_t)NN * HH * 2);         //   4 MB (alias xb)
    u16*      t1b    = (u16*)alloc((size_t)NN * HH * 2);         //   4 MB (alias h1b)
    u16*      xhb    = (u16*)alloc((size_t)NN * 768 * 2);        //  12 MB (alias hcatb)
    float*    vdot   = (float*)alloc((size_t)NN * HH * 4);       //   8 MB (alias heng)
    u16*      vpb    = (u16*)alloc((size_t)NN * 1536 * 2);       //  24 MB (alias accV)
    float*    accX   = (float*)alloc((size_t)NN * HH * 4);       //   8 MB (msg atomic acc)
    u16*      houtb  = (u16*)alloc((size_t)NN * 768 * 2);        //  12 MB
    float*    ev     = (float*)alloc((size_t)EE * 4 * 4);        //   2 MB
    int*      deg    = (int*)alloc((size_t)NN * 4);
    int*      fill   = (int*)alloc((size_t)NN * 4);
    int*      srcp   = (int*)alloc((size_t)EE * 4);
    int*      dstp   = (int*)alloc((size_t)EE * 4);              // 0.5 MB
    float4*   evp    = (float4*)alloc((size_t)EE * 16);          //   2 MB
    int*      kptab  = (int*)alloc((size_t)EE * 4);              // 0.5 MB
    unsigned* gtab   = (unsigned*)alloc((size_t)EE * 16);        //   2 MB (bf16 pairs)
    u16* xp_w1T   = (u16*)alloc((size_t)3 * 256 * 256 * 2);
    u16* xp_w2T   = (u16*)alloc((size_t)3 * 768 * 256 * 2);
    u16* rbf_wP   = (u16*)alloc((size_t)3 * 128 * 768 * 2);      // pair-interleaved bf16
    u16* vec_wT   = (u16*)alloc((size_t)3 * 512 * 256 * 2);
    u16* xv_w1T   = (u16*)alloc((size_t)3 * 256 * 512 * 2);
    u16* xv_w2T   = (u16*)alloc((size_t)3 * 768 * 256 * 2);
    u16* oe_w1T   = (u16*)alloc((size_t)128 * 256 * 2);
    (void)ws_size;

    u16*   h1b   = t1b;
    u16*   hcatb = xhb;
    float* heng  = vdot;
    u16*   xb    = xlnb;
    float* accV  = (float*)vpb;    // 24 MB alias: zeroed in k_update_out after last read

    // ---- setup ----
    k_wt_all<<<2432, 256, 0, stream>>>(xp_w1, xp_w2, rbf_w, vec_w, xv_w1, xv_w2, oe_w1,
                                       xp_w1T, xp_w2T, rbf_wP, vec_wT, xv_w1T, xv_w2T, oe_w1T);
    k_zero<<<(36 * 1024 * 1024 / 16 + 255) / 256, 256, 0, stream>>>(vecA, 36 * 1024 * 1024 / 16);
    // zero atomic accumulators for layer 0: vpb(24MB)+accX(8MB) are adjacent
    k_zero<<<(32 * 1024 * 1024 / 16 + 255) / 256, 256, 0, stream>>>((float*)vpb, 32 * 1024 * 1024 / 16);
    k_zero<<<8, 256, 0, stream>>>((float*)deg, NN / 4);
    k_init_ln<<<NN, 256, 0, stream>>>(atom_emb, z, ln_w, ln_b, x, xlnb);
    k_geom_hist<<<EE / 256, 256, 0, stream>>>(pos, ei, ev, deg);
    k_scan<<<1, 256, 0, stream>>>(deg, fill);
    k_scatter<<<EE / 256, 256, 0, stream>>>(ei, ev, fill, srcp, evp, kptab, gtab, dstp);

    for (int l = 0; l < LL; ++l) {
        // ---- PaiNNMessage ----
        k_gemm<1, 1><<<dim3(2, NN / 128), 256, 0, stream>>>(
            xlnb, xp_w1T + (size_t)l * 256 * 256, xp_b1 + l * HH, t1b, NN, 256, 256);
        k_gemm<1, 0><<<dim3(6, NN / 128), 256, 0, stream>>>(
            t1b, xp_w2T + (size_t)l * 768 * 256, xp_b2 + l * 768, xhb, NN, 256, 768);
        k_msg<<<EE / (CHUNK * MSG_WAVES), 1024, 0, stream>>>(
            xhb, vb, srcp, evp, dstp, kptab, gtab,
            rbf_wP + (size_t)l * 128 * 768, rbf_b + l * 768, accX, accV);
        k_msg_epi<<<NN, 256, 0, stream>>>(accX, accV, x, vecA, vecMb);

        // ---- PaiNNUpdate ----
        k_gemm<1, 0><<<dim3(4, 3 * NN / 128), 256, 0, stream>>>(
            vecMb, vec_wT + (size_t)l * 512 * 256, nullptr, vpb, 3 * NN, 256, 512);
        k_vecdot<<<NN, 256, 0, stream>>>(vpb, x, vdot, hcatb);
        k_gemm<1, 1><<<dim3(2, NN / 128), 256, 0, stream>>>(
            hcatb, xv_w1T + (size_t)l * 256 * 512, xv_b1 + l * HH, h1b, NN, 512, 256);
        k_gemm<1, 0><<<dim3(6, NN / 128), 256, 0, stream>>>(
            h1b, xv_w2T + (size_t)l * 768 * 256, xv_b2 + l * 768, houtb, NN, 256, 768);
        bool last = (l == LL - 1);
        k_update_out<<<NN, 256, 0, stream>>>(
            houtb, vdot, vpb, x, vecMb, vecA, vb,
            last ? nullptr : ln_w + (l + 1) * HH,
            last ? nullptr : ln_b + (l + 1) * HH, xlnb,
            last ? nullptr : accX, last ? nullptr : accV);
    }

    // ---- energy head ----
    k_gemm<0, 1><<<dim3(1, NN / 128), 256, 0, stream>>>(
        xb, oe_w1T, oe_b1, heng, NN, 256, 128);
    k_zero<<<1, 256, 0, stream>>>(out, NGG / 4);
    k_energy2<<<32, 256, 0, stream>>>(heng, oe_w2, oe_b2, batch, out);
}

// Round 2
// 831.380 us; speedup vs baseline: 1.9978x; 1.9978x over previous
//
#include <hip/hip_runtime.h>
#include <hip/hip_bf16.h>
#include <math.h>

#define NN 8192
#define EE 131072
#define HH 256
#define LL 3
#define RR 128
#define NGG 64
#define MSG_WAVES 16         // waves per k_msg block (1024 threads)
#define CHUNK 16             // edges per wave: EE/CHUNK = 8192 waves, perfectly uniform

typedef __attribute__((ext_vector_type(8))) short bf16x8;
typedef __attribute__((ext_vector_type(4))) float f32x4;
typedef unsigned short u16;

#if defined(__has_builtin)
#if __has_builtin(__builtin_amdgcn_fdot2_f32_bf16)
#define HAVE_FDOT2 1
typedef __attribute__((ext_vector_type(2))) __bf16 bf16x2_t;
union BU { unsigned u; bf16x2_t v; };
#endif
#if __has_builtin(__builtin_amdgcn_global_load_lds)
#define HAVE_GLL 1
#endif
#endif

union U4 { ushort4 v; unsigned short a[4]; };
union U8 { uint4 v; unsigned short a[8]; unsigned w[4]; };

__device__ __forceinline__ float silu(float v) { return v / (1.0f + expf(-v)); }
__device__ __forceinline__ float b2f(unsigned short u) { return __uint_as_float(((unsigned)u) << 16); }
__device__ __forceinline__ unsigned short f2b(float f) {
    unsigned u = __float_as_uint(f);
    u += 0x7fff + ((u >> 16) & 1);
    return (unsigned short)(u >> 16);
}

constexpr float kInvSqrt2 = 0.70710678118654752440f;
constexpr float kInvSqrt3 = 0.57735026918962576451f;
constexpr float kInvSqrtH = 0.0625f; // 1/sqrt(256)

// ---------------- utility ----------------
__global__ void k_zero(float* __restrict__ p, int n4) {
    int i = blockIdx.x * 256 + threadIdx.x;
    if (i < n4) ((float4*)p)[i] = make_float4(0.f, 0.f, 0.f, 0.f);
}

// ---------------- ALL weight prep in one launch ----------------
// transpose in[K,N] fp32 -> out[N,K] bf16; rbf_w: row-PAIR interleaved k-major bf16
__global__ __launch_bounds__(256) void k_wt_all(
    const float* __restrict__ xp_w1, const float* __restrict__ xp_w2,
    const float* __restrict__ rbf_w, const float* __restrict__ vec_w,
    const float* __restrict__ xv_w1, const float* __restrict__ xv_w2,
    const float* __restrict__ oe_w1,
    u16* __restrict__ xp_w1T, u16* __restrict__ xp_w2T, u16* __restrict__ rbf_wP,
    u16* __restrict__ vec_wT, u16* __restrict__ xv_w1T, u16* __restrict__ xv_w2T,
    u16* __restrict__ oe_w1T) {
    int bid = blockIdx.x;
    const float* src; u16* dst; int K, N, t, pairmode = 0;
    if (bid < 2400) {
        int l = bid / 800, r = bid % 800;
        if (r < 64)       { src = xp_w1 + (size_t)l * 65536;  dst = xp_w1T + (size_t)l * 65536;  K = 256; N = 256; t = r; }
        else if (r < 256) { src = xp_w2 + (size_t)l * 196608; dst = xp_w2T + (size_t)l * 196608; K = 256; N = 768; t = r - 64; }
        else if (r < 352) { src = rbf_w + (size_t)l * 98304;  dst = rbf_wP + (size_t)l * 98304;  K = 128; N = 768; t = r - 256; pairmode = 1; }
        else if (r < 480) { src = vec_w + (size_t)l * 131072; dst = vec_wT + (size_t)l * 131072; K = 256; N = 512; t = r - 352; }
        else if (r < 608) { src = xv_w1 + (size_t)l * 131072; dst = xv_w1T + (size_t)l * 131072; K = 512; N = 256; t = r - 480; }
        else              { src = xv_w2 + (size_t)l * 196608; dst = xv_w2T + (size_t)l * 196608; K = 256; N = 768; t = r - 608; }
    } else {
        src = oe_w1; dst = oe_w1T; K = 256; N = 128; t = bid - 2400;
    }
    int nx = N >> 5;
    int bn = (t % nx) * 32, bk = (t / nx) * 32;
    int tx = threadIdx.x & 31, ty = threadIdx.x >> 5;   // 32 x 8
    if (pairmode) {
#pragma unroll
        for (int i = 0; i < 32; i += 8) {
            int k = bk + ty + i, n = bn + tx;
            dst[(size_t)(k >> 1) * 1536 + n * 2 + (k & 1)] = f2b(src[(size_t)k * N + n]);
        }
        return;
    }
    __shared__ float tile[32][33];
#pragma unroll
    for (int i = 0; i < 32; i += 8)
        tile[ty + i][tx] = src[(size_t)(bk + ty + i) * N + bn + tx];
    __syncthreads();
#pragma unroll
    for (int i = 0; i < 32; i += 8)
        dst[(size_t)(bn + ty + i) * K + bk + tx] = f2b(tile[tx][ty + i]);
}

// ---------------- init: x = atom_emb[z], + LayerNorm(ln[0]) -> xlnb ----------------
__global__ void k_init_ln(const float* __restrict__ emb, const int* __restrict__ z,
                          const float* __restrict__ w, const float* __restrict__ b,
                          float* __restrict__ x, u16* __restrict__ xlnb) {
    int n = blockIdx.x, t = threadIdx.x;
    float v = emb[z[n] * HH + t];
    x[(size_t)n * HH + t] = v;
    float s = v, q = v * v;
#pragma unroll
    for (int m = 32; m >= 1; m >>= 1) {
        s += __shfl_xor(s, m, 64);
        q += __shfl_xor(q, m, 64);
    }
    __shared__ float s_sum[4], s_sq[4];
    int wid = t >> 6;
    if ((t & 63) == 0) { s_sum[wid] = s; s_sq[wid] = q; }
    __syncthreads();
    float S = s_sum[0] + s_sum[1] + s_sum[2] + s_sum[3];
    float Q = s_sq[0] + s_sq[1] + s_sq[2] + s_sq[3];
    float mu = S * (1.0f / HH);
    float var = Q * (1.0f / HH) - mu * mu;
    float rs = rsqrtf(var + 1e-5f);
    xlnb[(size_t)n * HH + t] = f2b((v - mu) * rs * w[t] + b[t]);
}

// ---------------- edge geometry + degree histogram (fused) ----------------
__global__ void k_geom_hist(const float* __restrict__ pos, const int* __restrict__ ei,
                            float* __restrict__ ev, int* __restrict__ deg) {
    int e = blockIdx.x * 256 + threadIdx.x;
    if (e >= EE) return;
    int s = ei[e], d = ei[EE + e];
    float rx = pos[s * 3 + 0] - pos[d * 3 + 0];
    float ry = pos[s * 3 + 1] - pos[d * 3 + 1];
    float rz = pos[s * 3 + 2] - pos[d * 3 + 2];
    float dist = sqrtf(rx * rx + ry * ry + rz * rz);
    float inv = 1.0f / dist;
    ((float4*)ev)[e] = make_float4(rx * inv, ry * inv, rz * inv, dist);
    atomicAdd(&deg[d], 1);
}

// ---------------- scan (CSR row_ptr + fill), one block ---------------
__global__ void k_scan(const int* __restrict__ deg, int* __restrict__ row_ptr,
                       int* __restrict__ fill) {
    __shared__ int buf[256];
    __shared__ int carry_s;
    int t = threadIdx.x;
    if (t == 0) carry_s = 0;
    __syncthreads();
    for (int r = 0; r < NN; r += 256) {
        int v = deg[r + t];
        buf[t] = v;
        __syncthreads();
        for (int ofs = 1; ofs < 256; ofs <<= 1) {
            int add = (t >= ofs) ? buf[t - ofs] : 0;
            __syncthreads();
            buf[t] += add;
            __syncthreads();
        }
        int excl = buf[t] - v;
        int carry = carry_s;
        row_ptr[r + t] = carry + excl;
        fill[r + t] = carry + excl;
        __syncthreads();
        if (t == 255) carry_s = carry + buf[t];
        __syncthreads();
    }
    if (t == 0) row_ptr[NN] = carry_s;
}

// scatter + gaussian window: 8 rows, EVEN-aligned k0; gtab packed bf16 pairs (16B)
__global__ void k_scatter(const int* __restrict__ ei, const float* __restrict__ ev,
                          int* __restrict__ fill, int* __restrict__ srcp,
                          float4* __restrict__ evp, int* __restrict__ kptab,
                          unsigned* __restrict__ gtab, int* __restrict__ dstp) {
    int e = blockIdx.x * 256 + threadIdx.x;
    if (e >= EE) return;
    int d = ei[EE + e];
    int pos = atomicAdd(&fill[d], 1);
    float4 e4 = ((const float4*)ev)[e];
    srcp[pos] = ei[e];
    dstp[pos] = d;
    evp[pos] = e4;
    const float step = 12.0f / 127.0f;
    const float coeff = -0.5f / (step * step);
    float dist = e4.w;
    int k0 = ((int)floorf(dist / step) - 3) & ~1;   // even-aligned
    k0 = k0 < 0 ? 0 : (k0 > 120 ? 120 : k0);
    float g[8];
#pragma unroll
    for (int k = 0; k < 8; ++k) {
        float t = dist - (k0 + k) * step;
        g[k] = expf(coeff * t * t);
    }
    kptab[pos] = k0 >> 1;
    unsigned g0 = (unsigned)f2b(g[0]) | ((unsigned)f2b(g[1]) << 16);
    unsigned g1 = (unsigned)f2b(g[2]) | ((unsigned)f2b(g[3]) << 16);
    unsigned g2 = (unsigned)f2b(g[4]) | ((unsigned)f2b(g[5]) << 16);
    unsigned g3 = (unsigned)f2b(g[6]) | ((unsigned)f2b(g[7]) << 16);
    ((uint4*)gtab)[pos] = make_uint4(g0, g1, g2, g3);
}

// ---------------- bf16 MFMA GEMM: C = act(A[M,K] @ BT[N,K]^T + bias) ----------------
template <int OUT_BF16, int ACT>
__global__ __launch_bounds__(256) void k_gemm(
    const u16* __restrict__ A, const u16* __restrict__ BT,
    const float* __restrict__ bias, void* __restrict__ C, int M, int K, int N) {
    __shared__ u16 As[4096];   // [128 rows][32 k] bf16 = 8 KB
    __shared__ u16 Bs[4096];
    int tid = threadIdx.x;
    int wave = tid >> 6, lane = tid & 63;
    int bm = blockIdx.y * 128, bn = blockIdx.x * 128;
    int wm = (wave >> 1) * 64, wn = (wave & 1) * 64;
    int lm = lane & 15;
    int kg = lane >> 4;
    f32x4 acc[4][4] = {};

    for (int k0 = 0; k0 < K; k0 += 32) {
#pragma unroll
        for (int it = 0; it < 2; ++it) {
            int idx = it * 256 + tid;
            int r = idx >> 2, seg = idx & 3;
#ifdef HAVE_GLL
            __builtin_amdgcn_global_load_lds(
                (const unsigned*)&A[(size_t)(bm + r) * K + k0 + seg * 8],
                (unsigned*)&As[idx * 8], 16, 0, 0);
            __builtin_amdgcn_global_load_lds(
                (const unsigned*)&BT[(size_t)(bn + r) * K + k0 + seg * 8],
                (unsigned*)&Bs[idx * 8], 16, 0, 0);
#else
            *(uint4*)&As[idx * 8] = *(const uint4*)&A[(size_t)(bm + r) * K + k0 + seg * 8];
            *(uint4*)&Bs[idx * 8] = *(const uint4*)&BT[(size_t)(bn + r) * K + k0 + seg * 8];
#endif
        }
        __syncthreads();
        bf16x8 af[4], bfr[4];
#pragma unroll
        for (int i = 0; i < 4; ++i)
            af[i] = *(const bf16x8*)&As[(wm + i * 16 + lm) * 32 + kg * 8];
#pragma unroll
        for (int j = 0; j < 4; ++j)
            bfr[j] = *(const bf16x8*)&Bs[(wn + j * 16 + lm) * 32 + kg * 8];
#pragma unroll
        for (int i = 0; i < 4; ++i)
#pragma unroll
            for (int j = 0; j < 4; ++j)
                acc[i][j] = __builtin_amdgcn_mfma_f32_16x16x32_bf16(af[i], bfr[j], acc[i][j], 0, 0, 0);
        __syncthreads();
    }

#pragma unroll
    for (int j = 0; j < 4; ++j) {
        int col = bn + wn + j * 16 + lm;
        float bv = bias ? bias[col] : 0.f;
#pragma unroll
        for (int i = 0; i < 4; ++i) {
            int row0 = bm + wm + i * 16 + kg * 4;
#pragma unroll
            for (int r = 0; r < 4; ++r) {
                float v = acc[i][j][r] + bv;
                if (ACT) v = silu(v);
                if (OUT_BF16)
                    ((u16*)C)[(size_t)(row0 + r) * N + col] = f2b(v);
                else
                    ((float*)C)[(size_t)(row0 + r) * N + col] = v;
            }
        }
    }
}

// ---------------- fused message pass: BALANCED chunks, DETERMINISTIC partials -------
// Every wave processes exactly CHUNK edges of the dst-sorted edge array (3 panels).
// Run ownership: run containing chunk-start -> bufA[wave]; run ending at chunk-end
// (and not containing start) -> bufB[wave]; strictly-interior run -> exclusive node,
// plain store to accX/accV. NO atomics anywhere. Epilogue reassembles per node.
// buf layout per wave: [0:256) x-partial, [256+k*256 + c) v-partial (k=0..2).
__global__ __launch_bounds__(1024) void k_msg(
    const u16* __restrict__ xhb, const u16* __restrict__ vinb,
    const int* __restrict__ srcp, const float4* __restrict__ evp,
    const int* __restrict__ dstp, const int* __restrict__ kptab,
    const unsigned* __restrict__ gtab, const u16* __restrict__ WP /*pair-interleaved*/,
    const float* __restrict__ rbias,
    float* __restrict__ accX, float* __restrict__ accV,
    float* __restrict__ bufA, float* __restrict__ bufB) {
    __shared__ u16 Wp[64 * 512];    // 64 KB: [64 row-pairs][256 cols][2]
    int tid = threadIdx.x;
    int wave = tid >> 6, lane = tid & 63;
    int c0 = lane * 4;
    int gw = blockIdx.x * MSG_WAVES + wave;
    int E0 = gw * CHUNK, E1 = E0 + CHUNK;
    float* bA = bufA + (size_t)gw * 1024;
    float* bB = bufB + (size_t)gw * 1024;

#pragma unroll
    for (int p = 0; p < 3; ++p) {
        __syncthreads();
#pragma unroll
        for (int it = 0; it < 4; ++it) {        // cooperative 64KB panel load
            int idx = it * 1024 + tid;          // 4096 uint4
            int r = idx >> 6;                   // 64 row-pairs, 64 uint4/pair
            int c8 = (idx & 63) * 8;
            *(uint4*)&Wp[r * 512 + c8] =
                *(const uint4*)&WP[(size_t)r * 1536 + p * 512 + c8];
        }
        __syncthreads();
        float4 bb = ((const float4*)(rbias + p * 256))[lane];
        float bias4[4] = {bb.x, bb.y, bb.z, bb.w};
        float acc[3][4] = {};                   // p==0 uses acc[0] only
        int dcur = dstp[E0];
        int rs = E0;                            // current run start
        auto flush = [&](int dn, int rstart, int atEnd) {
            int isFirst = (rstart == E0);
            if (p == 0) {
                float* q = isFirst ? bA : (atEnd ? bB : accX + (size_t)dn * 256);
                *(float4*)&q[c0] = make_float4(acc[0][0], acc[0][1], acc[0][2], acc[0][3]);
            } else {
                float* q = isFirst ? bA + 256 : (atEnd ? bB + 256 : accV + (size_t)dn * 768);
                if (p == 1) {
#pragma unroll
                    for (int k = 0; k < 3; ++k)
                        *(float4*)&q[k * 256 + c0] =
                            make_float4(acc[k][0], acc[k][1], acc[k][2], acc[k][3]);
                } else {  // p==2: read-add-store; exclusive owner, no atomics needed
#pragma unroll
                    for (int k = 0; k < 3; ++k) {
                        float4 o = *(const float4*)&q[k * 256 + c0];
                        o.x += acc[k][0]; o.y += acc[k][1];
                        o.z += acc[k][2]; o.w += acc[k][3];
                        *(float4*)&q[k * 256 + c0] = o;
                    }
                }
            }
#pragma unroll
            for (int k = 0; k < 3; ++k)
#pragma unroll
                for (int c = 0; c < 4; ++c) acc[k][c] = 0.f;
        };
#pragma unroll 2
        for (int j = E0; j < E1; ++j) {
            int d = dstp[j];
            if (d != dcur) { flush(dcur, rs, 0); dcur = d; rs = j; }  // wave-uniform
            int s = srcp[j];
            int kp = kptab[j];
            uint4 gt = ((const uint4*)gtab)[j];
            unsigned gp[4] = {gt.x, gt.y, gt.z, gt.w};
            float rr[4] = {bias4[0], bias4[1], bias4[2], bias4[3]};
#pragma unroll
            for (int p2 = 0; p2 < 4; ++p2) {
                U8 w;
                w.v = *(const uint4*)&Wp[(kp + p2) * 512 + c0 * 2];  // ds_read_b128
#ifdef HAVE_FDOT2
                BU gv; gv.u = gp[p2];
#pragma unroll
                for (int c = 0; c < 4; ++c) {
                    BU wv; wv.u = w.w[c];
                    rr[c] = __builtin_amdgcn_fdot2_f32_bf16(wv.v, gv.v, rr[c], false);
                }
#else
                float ge = b2f((u16)(gp[p2] & 0xffff));
                float go = b2f((u16)(gp[p2] >> 16));
#pragma unroll
                for (int c = 0; c < 4; ++c)
                    rr[c] += ge * b2f(w.a[2 * c]) + go * b2f(w.a[2 * c + 1]);
#endif
            }
            if (p == 0) {
                U4 X; X.v = *(const ushort4*)(xhb + (size_t)s * 768 + c0);
#pragma unroll
                for (int c = 0; c < 4; ++c) acc[0][c] += b2f(X.a[c]) * rr[c];
            } else if (p == 1) {
                U4 X, V0, V1, V2;
                X.v = *(const ushort4*)(xhb + (size_t)s * 768 + 256 + c0);
                V0.v = *(const ushort4*)(vinb + (size_t)s * 768 + c0);
                V1.v = *(const ushort4*)(vinb + (size_t)s * 768 + 256 + c0);
                V2.v = *(const ushort4*)(vinb + (size_t)s * 768 + 512 + c0);
#pragma unroll
                for (int c = 0; c < 4; ++c) {
                    float m1 = b2f(X.a[c]) * rr[c] * kInvSqrt3;
                    acc[0][c] += b2f(V0.a[c]) * m1;
                    acc[1][c] += b2f(V1.a[c]) * m1;
                    acc[2][c] += b2f(V2.a[c]) * m1;
                }
            } else {
                U4 X; X.v = *(const ushort4*)(xhb + (size_t)s * 768 + 512 + c0);
                float4 ev4 = evp[j];
#pragma unroll
                for (int c = 0; c < 4; ++c) {
                    float m2 = b2f(X.a[c]) * rr[c];
                    acc[0][c] += m2 * ev4.x;
                    acc[1][c] += m2 * ev4.y;
                    acc[2][c] += m2 * ev4.z;
                }
            }
        }
        flush(dcur, rs, 1);
    }
}

// ---------------- message epilogue: reassemble node sums from partials --------------
// node n, edges [e0,e1): covering waves w0..w1. Contribution of w0 is bufA[w0] if
// e0 chunk-aligned else bufB[w0]; waves w0<w<=w1 contribute bufA[w]. If the node is
// strictly inside one chunk it was direct-stored to accX/accV.
__global__ void k_msg_epi(const int* __restrict__ row_ptr,
                          const float* __restrict__ accX, const float* __restrict__ accV,
                          const float* __restrict__ bufA, const float* __restrict__ bufB,
                          float* __restrict__ x, const float* __restrict__ vin,
                          u16* __restrict__ vecMb) {
    int n = blockIdx.x, t = threadIdx.x;   // 256 threads = channels
    int e0 = row_ptr[n], e1 = row_ptr[n + 1];
    float ax = 0.f, av0 = 0.f, av1 = 0.f, av2 = 0.f;
    if (e1 > e0) {
        int w0 = e0 >> 4, w1 = (e1 - 1) >> 4;
        bool direct = (w0 == w1) && ((e0 & (CHUNK - 1)) != 0) && ((e1 & (CHUNK - 1)) != 0);
        if (direct) {
            ax  = accX[(size_t)n * 256 + t];
            av0 = accV[(size_t)n * 768 + t];
            av1 = accV[(size_t)n * 768 + 256 + t];
            av2 = accV[(size_t)n * 768 + 512 + t];
        } else {
            const float* q = ((e0 & (CHUNK - 1)) == 0) ? bufA + (size_t)w0 * 1024
                                                       : bufB + (size_t)w0 * 1024;
            ax  += q[t];
            av0 += q[256 + t];
            av1 += q[512 + t];
            av2 += q[768 + t];
            for (int w = w0 + 1; w <= w1; ++w) {
                const float* r = bufA + (size_t)w * 1024;
                ax  += r[t];
                av0 += r[256 + t];
                av1 += r[512 + t];
                av2 += r[768 + t];
            }
        }
    }
    size_t xi = (size_t)n * 256 + t;
    float nx = (x[xi] + ax) * kInvSqrt2;
    x[xi] = nx;
    size_t vi = (size_t)n * 768 + t;
    vecMb[vi]       = f2b(vin[vi]       + av0 * kInvSqrtH);
    vecMb[vi + 256] = f2b(vin[vi + 256] + av1 * kInvSqrtH);
    vecMb[vi + 512] = f2b(vin[vi + 512] + av2 * kInvSqrtH);
}

// ---------------- vec_dot + hcat(bf16) = [x, vnorm]; vp in bf16 -------------------
__global__ void k_vecdot(const u16* __restrict__ vp, const float* __restrict__ x,
                         float* __restrict__ vec_dot, u16* __restrict__ hcat) {
    int i = blockIdx.x * 256 + threadIdx.x;  // N*H
    int n = i >> 8, c = i & 255;
    const u16* p = vp + (size_t)n * 1536;
    float dsum = 0.f, qsum = 0.f;
#pragma unroll
    for (int k = 0; k < 3; ++k) {
        float v1 = b2f(p[k * 512 + c]);
        float v2 = b2f(p[k * 512 + 256 + c]);
        dsum += v1 * v2;
        qsum += v2 * v2;
    }
    vec_dot[i] = dsum * kInvSqrtH;
    hcat[(size_t)n * 512 + c] = f2b(x[i]);
    hcat[(size_t)n * 512 + 256 + c] = f2b(sqrtf(qsum + 1e-8f));
}

// ---------------- update epilogue + fused LayerNorm ----------------
__global__ void k_update_out(const u16* __restrict__ hout, const float* __restrict__ vec_dot,
                             const u16* __restrict__ vp, float* __restrict__ x,
                             const u16* __restrict__ vecMb, float* __restrict__ vfin,
                             u16* __restrict__ vb,
                             const float* __restrict__ lnw, const float* __restrict__ lnb,
                             u16* __restrict__ xout) {
    int n = blockIdx.x, t = threadIdx.x;
    size_t i = (size_t)n * 256 + t;
    float xv1 = b2f(hout[(size_t)n * 768 + t]);
    float xv2 = b2f(hout[(size_t)n * 768 + 256 + t]);
    float xv3 = b2f(hout[(size_t)n * 768 + 512 + t]);
    float dxv = (xv1 + xv2 * vec_dot[i]) * kInvSqrt2;
    float nx = (x[i] + dxv) * kInvSqrt2;
    x[i] = nx;
#pragma unroll
    for (int k = 0; k < 3; ++k) {
        size_t idx = (size_t)n * 768 + k * 256 + t;
        float nv = b2f(vecMb[idx]) + xv3 * b2f(vp[(size_t)n * 1536 + k * 512 + t]);
        vfin[idx] = nv;
        vb[idx] = f2b(nv);
    }
    if (lnw) {
        float s = nx, q = nx * nx;
#pragma unroll
        for (int m = 32; m >= 1; m >>= 1) {
            s += __shfl_xor(s, m, 64);
            q += __shfl_xor(q, m, 64);
        }
        __shared__ float s_sum[4], s_sq[4];
        int wid = t >> 6;
        if ((t & 63) == 0) { s_sum[wid] = s; s_sq[wid] = q; }
        __syncthreads();
        float S = s_sum[0] + s_sum[1] + s_sum[2] + s_sum[3];
        float Q = s_sq[0] + s_sq[1] + s_sq[2] + s_sq[3];
        float mu = S * (1.0f / HH);
        float var = Q * (1.0f / HH) - mu * mu;
        float rs = rsqrtf(var + 1e-5f);
        xout[i] = f2b((nx - mu) * rs * lnw[t] + lnb[t]);
    } else {
        xout[i] = f2b(nx);
    }
}

// ---------------- energy reduce ----------------
__global__ void k_energy2(const float* __restrict__ h, const float* __restrict__ w2,
                          const float* __restrict__ b2, const int* __restrict__ batch,
                          float* __restrict__ out) {
    __shared__ float g[NGG];
    int t = threadIdx.x;
    if (t < NGG) g[t] = 0.f;
    __syncthreads();
    int a = blockIdx.x * 256 + t;
    const float4* hr = (const float4*)(h + (size_t)a * 128);
    const float4* w4 = (const float4*)w2;
    float acc = 0.f;
#pragma unroll 8
    for (int i = 0; i < 32; ++i) {
        float4 hv = hr[i], wv = w4[i];
        acc += hv.x * wv.x + hv.y * wv.y + hv.z * wv.z + hv.w * wv.w;
    }
    acc += b2[0];
    atomicAdd(&g[batch[a]], acc);
    __syncthreads();
    if (t < NGG && g[t] != 0.f) atomicAdd(&out[t], g[t]);
}

extern "C" void kernel_launch(void* const* d_in, const int* in_sizes, int n_in,
                              void* d_out, int out_size, void* d_ws, size_t ws_size,
                              hipStream_t stream) {
    const float* pos      = (const float*)d_in[0];
    const float* atom_emb = (const float*)d_in[1];
    const float* ln_w     = (const float*)d_in[2];
    const float* ln_b     = (const float*)d_in[3];
    const float* xp_w1    = (const float*)d_in[4];
    const float* xp_b1    = (const float*)d_in[5];
    const float* xp_w2    = (const float*)d_in[6];
    const float* xp_b2    = (const float*)d_in[7];
    const float* rbf_w    = (const float*)d_in[8];
    const float* rbf_b    = (const float*)d_in[9];
    const float* vec_w    = (const float*)d_in[10];
    const float* xv_w1    = (const float*)d_in[11];
    const float* xv_b1    = (const float*)d_in[12];
    const float* xv_w2    = (const float*)d_in[13];
    const float* xv_b2    = (const float*)d_in[14];
    const float* oe_w1    = (const float*)d_in[15];
    const float* oe_b1    = (const float*)d_in[16];
    const float* oe_w2    = (const float*)d_in[17];
    const float* oe_b2    = (const float*)d_in[18];
    const int*   z        = (const int*)d_in[19];
    const int*   ei       = (const int*)d_in[20];
    const int*   batch    = (const int*)d_in[21];
    float* out = (float*)d_out;

    char* ws = (char*)d_ws;
    size_t off = 0;
    auto alloc = [&](size_t b) {
        void* p = ws + off;
        off = (off + b + 255) & ~(size_t)255;
        return p;
    };
    float*    x      = (float*)alloc((size_t)NN * HH * 4);       //   8 MB
    float*    vecA   = (float*)alloc((size_t)NN * 768 * 4);      //  24 MB  \ adjacent:
    u16*      vb     = (u16*)alloc((size_t)NN * 768 * 2);        //  12 MB  / joint zero
    u16*      vecMb  = (u16*)alloc((size_t)NN * 768 * 2);        //  12 MB
    u16*      xlnb   = (u16*)alloc((size_t)NN * HH * 2);         //   4 MB (alias xb)
    u16*      t1b    = (u16*)alloc((size_t)NN * HH * 2);         //   4 MB (alias h1b)
    u16*      xhb    = (u16*)alloc((size_t)NN * 768 * 2);        //  12 MB (alias hcatb)
    float*    vdot   = (float*)alloc((size_t)NN * HH * 4);       //   8 MB (alias heng)
    u16*      vpb    = (u16*)alloc((size_t)NN * 1536 * 2);       //  24 MB (alias accV)
    float*    accX   = (float*)alloc((size_t)NN * HH * 4);       //   8 MB (msg direct x)
    float*    bufA   = (float*)alloc((size_t)EE / CHUNK * 1024 * 4); // 32 MB wave partials
    float*    bufB   = (float*)alloc((size_t)EE / CHUNK * 1024 * 4); // 32 MB
    u16*      houtb  = (u16*)alloc((size_t)NN * 768 * 2);        //  12 MB
    float*    ev     = (float*)alloc((size_t)EE * 4 * 4);        //   2 MB
    int*      deg    = (int*)alloc((size_t)NN * 4);
    int*      row_ptr= (int*)alloc((size_t)(NN + 1) * 4);
    int*      fill   = (int*)alloc((size_t)NN * 4);
    int*      srcp   = (int*)alloc((size_t)EE * 4);
    int*      dstp   = (int*)alloc((size_t)EE * 4);              // 0.5 MB
    float4*   evp    = (float4*)alloc((size_t)EE * 16);          //   2 MB
    int*      kptab  = (int*)alloc((size_t)EE * 4);              // 0.5 MB
    unsigned* gtab   = (unsigned*)alloc((size_t)EE * 16);        //   2 MB (bf16 pairs)
    u16* xp_w1T   = (u16*)alloc((size_t)3 * 256 * 256 * 2);
    u16* xp_w2T   = (u16*)alloc((size_t)3 * 768 * 256 * 2);
    u16* rbf_wP   = (u16*)alloc((size_t)3 * 128 * 768 * 2);      // pair-interleaved bf16
    u16* vec_wT   = (u16*)alloc((size_t)3 * 512 * 256 * 2);
    u16* xv_w1T   = (u16*)alloc((size_t)3 * 256 * 512 * 2);
    u16* xv_w2T   = (u16*)alloc((size_t)3 * 768 * 256 * 2);
    u16* oe_w1T   = (u16*)alloc((size_t)128 * 256 * 2);
    (void)ws_size;

    u16*   h1b   = t1b;
    u16*   hcatb = xhb;
    float* heng  = vdot;
    u16*   xb    = xlnb;
    float* accV  = (float*)vpb;    // 24 MB alias: msg direct-stores, then gemm overwrites

    // ---- setup ----
    k_wt_all<<<2432, 256, 0, stream>>>(xp_w1, xp_w2, rbf_w, vec_w, xv_w1, xv_w2, oe_w1,
                                       xp_w1T, xp_w2T, rbf_wP, vec_wT, xv_w1T, xv_w2T, oe_w1T);
    k_zero<<<(36 * 1024 * 1024 / 16 + 255) / 256, 256, 0, stream>>>(vecA, 36 * 1024 * 1024 / 16);
    k_zero<<<8, 256, 0, stream>>>((float*)deg, NN / 4);
    k_init_ln<<<NN, 256, 0, stream>>>(atom_emb, z, ln_w, ln_b, x, xlnb);
    k_geom_hist<<<EE / 256, 256, 0, stream>>>(pos, ei, ev, deg);
    k_scan<<<1, 256, 0, stream>>>(deg, row_ptr, fill);
    k_scatter<<<EE / 256, 256, 0, stream>>>(ei, ev, fill, srcp, evp, kptab, gtab, dstp);

    for (int l = 0; l < LL; ++l) {
        // ---- PaiNNMessage ----
        k_gemm<1, 1><<<dim3(2, NN / 128), 256, 0, stream>>>(
            xlnb, xp_w1T + (size_t)l * 256 * 256, xp_b1 + l * HH, t1b, NN, 256, 256);
        k_gemm<1, 0><<<dim3(6, NN / 128), 256, 0, stream>>>(
            t1b, xp_w2T + (size_t)l * 768 * 256, xp_b2 + l * 768, xhb, NN, 256, 768);
        k_msg<<<EE / (CHUNK * MSG_WAVES), 1024, 0, stream>>>(
            xhb, vb, srcp, evp, dstp, kptab, gtab,
            rbf_wP + (size_t)l * 128 * 768, rbf_b + l * 768, accX, accV, bufA, bufB);
        k_msg_epi<<<NN, 256, 0, stream>>>(row_ptr, accX, accV, bufA, bufB, x, vecA, vecMb);

        // ---- PaiNNUpdate ----
        k_gemm<1, 0><<<dim3(4, 3 * NN / 128), 256, 0, stream>>>(
            vecMb, vec_wT + (size_t)l * 512 * 256, nullptr, vpb, 3 * NN, 256, 512);
        k_vecdot<<<NN, 256, 0, stream>>>(vpb, x, vdot, hcatb);
        k_gemm<1, 1><<<dim3(2, NN / 128), 256, 0, stream>>>(
            hcatb, xv_w1T + (size_t)l * 256 * 512, xv_b1 + l * HH, h1b, NN, 512, 256);
        k_gemm<1, 0><<<dim3(6, NN / 128), 256, 0, stream>>>(
            h1b, xv_w2T + (size_t)l * 768 * 256, xv_b2 + l * 768, houtb, NN, 256, 768);
        bool last = (l == LL - 1);
        k_update_out<<<NN, 256, 0, stream>>>(
            houtb, vdot, vpb, x, vecMb, vecA, vb,
            last ? nullptr : ln_w + (l + 1) * HH,
            last ? nullptr : ln_b + (l + 1) * HH, xlnb);
    }

    // ---- energy head ----
    k_gemm<0, 1><<<dim3(1, NN / 128), 256, 0, stream>>>(
        xb, oe_w1T, oe_b1, heng, NN, 256, 128);
    k_zero<<<1, 256, 0, stream>>>(out, NGG / 4);
    k_energy2<<<32, 256, 0, stream>>>(heng, oe_w2, oe_b2, batch, out);
}